// Round 1
// baseline (924.044 us; speedup 1.0000x reference)
//
#include <hip/hip_runtime.h>
#include <math.h>

#ifndef M_PI
#define M_PI 3.14159265358979323846
#endif

#define TPB 256

// Digit-reverse for 2048 = 4^5 * 2, radix sequence [4,4,4,4,4,2] (DIF order).
// Element with frequency index k lands at position drev11(k) after in-place DIF.
__device__ __forceinline__ int drev11(int k) {
  return ((k & 3) << 9) | (((k >> 2) & 3) << 7) | (((k >> 4) & 3) << 5)
       | (((k >> 6) & 3) << 3) | (((k >> 8) & 3) << 1) | ((k >> 10) & 1);
}

// W_N^k = e^{-i*pi*k/2048}, k in [0,2048]; Uc/Us hold cos/sin(pi*r/2048), r<512.
__device__ __forceinline__ void wn4096(int k, const double* Uc, const double* Us,
                                       double& wr, double& wi) {
  int q = k >> 9, r = k & 511;
  const double H = 0.7071067811865476;
  double pr  = (q == 0) ? 1.0 : (q == 1) ? H    : (q == 2) ? 0.0  : (q == 3) ? -H : -1.0;
  double pii = (q == 0) ? 0.0 : (q == 1) ? -H   : (q == 2) ? -1.0 : (q == 3) ? -H : 0.0;
  double ur = Uc[r], ui = -Us[r];
  wr = pr * ur - pii * ui;
  wi = pr * ui + pii * ur;
}

// |X[k]|^2 in fp64 from the digit-reversed packed spectrum Z.
__device__ __forceinline__ double exactMag2(int k, const double* Zr, const double* Zi,
                                            const double* Uc, const double* Us) {
  int ka = k & 2047, kb = (2048 - k) & 2047;
  int pa = drev11(ka), pb = drev11(kb);
  double zkr = Zr[pa], zki = Zi[pa], zmr = Zr[pb], zmi = Zi[pb];
  double her = 0.5 * (zkr + zmr), hei = 0.5 * (zki - zmi);
  double hor = 0.5 * (zki + zmi), hoi = -0.5 * (zkr - zmr);
  double wr, wi; wn4096(k, Uc, Us, wr, wi);
  double xr = her + wr * hor - wi * hoi;
  double xi = hei + wr * hoi + wi * hor;
  return xr * xr + xi * xi;
}

// (B, D1, D2) -> (B, D2, D1) tiled transpose; block (32,8), grid (D1/32, D2/32, B).
__global__ __launch_bounds__(TPB) void tpose_kernel(const float* __restrict__ in,
                                                    float* __restrict__ out,
                                                    int D1, int D2) {
  __shared__ float tile[32][33];
  int tx = threadIdx.x, ty = threadIdx.y;
  int b = blockIdx.z;
  int r0 = blockIdx.x * 32, c0 = blockIdx.y * 32;
  const float* ip = in + (size_t)b * D1 * D2;
  float* op = out + (size_t)b * D1 * D2;
#pragma unroll
  for (int j = 0; j < 32; j += 8)
    tile[ty + j][tx] = ip[(size_t)(r0 + ty + j) * D2 + (c0 + tx)];
  __syncthreads();
#pragma unroll
  for (int j = 0; j < 32; j += 8)
    op[(size_t)(c0 + ty + j) * D1 + (r0 + tx)] = tile[tx][ty + j];
}

// One block per (b,c) signal: fp64 packed rfft -> top-k mask -> irfft.
// strideT==1: src/dst are (B,C,S) contiguous. strideT==128: direct (B,S,C).
__global__ __launch_bounds__(TPB) void fourier_topk_kernel(
    const float* __restrict__ src, float* __restrict__ dst,
    const int* __restrict__ kptr, int strideT) {
  __shared__ double Zr[2048], Zi[2048];
  __shared__ double Wc[512], Ws[512], Uc[512], Us[512];
  __shared__ float keyF[2049];
  __shared__ unsigned int hist[512];
  __shared__ unsigned int scanBuf[256];
  __shared__ unsigned char maskArr[2052];
  __shared__ int tieIdx[64];
  __shared__ unsigned int bcD, bcR, bcCnt, bcT, bcG, bcE, bcTieN;

  const int tid = threadIdx.x;
  // XCD-aware swizzle: XCD j handles channels [16j, 16j+16) so strided-path
  // cache lines (16 floats = 16 channels) are shared within one XCD's L2.
  int i = blockIdx.x;
  int xj = i & 7, mm = i >> 3;
  int c = 16 * xj + (mm & 15);
  int b = mm >> 4;
  size_t base = (strideT == 1) ? ((size_t)(b * 128 + c)) * 4096
                               : ((size_t)b * 4096 * 128 + (size_t)c);
  const float* sp = src + base;
  float* dp = dst + base;

  // Twiddle tables (fp64): Wc/Ws = cos/sin(2*pi*j/2048); Uc/Us = cos/sin(pi*j/2048)
  for (int t = tid; t < 512; t += TPB) {
    double a1 = (M_PI / 1024.0) * t;
    Wc[t] = cos(a1); Ws[t] = sin(a1);
    double a2 = (M_PI / 2048.0) * t;
    Uc[t] = cos(a2); Us[t] = sin(a2);
  }
  // Load: z[n] = x[2n] + i*x[2n+1]
  for (int t = tid; t < 4096; t += TPB) {
    float v = sp[(size_t)t * strideT];
    if (t & 1) Zi[t >> 1] = (double)v; else Zr[t >> 1] = (double)v;
  }
  __syncthreads();

  // ---- forward FFT: in-place radix-4 DIF (natural -> digit-reversed) ----
#pragma unroll
  for (int n = 2048; n >= 8; n >>= 2) {
    const int mq = n >> 2;
    const int tw = 2048 / n;
#pragma unroll
    for (int uu = 0; uu < 2; ++uu) {
      int u = tid + uu * TPB;
      int blk = u / mq;
      int j = u - blk * mq;
      int b4 = blk * n + j;
      double ar = Zr[b4], ai = Zi[b4];
      double br = Zr[b4 + mq], bi = Zi[b4 + mq];
      double cr = Zr[b4 + 2 * mq], ci = Zi[b4 + 2 * mq];
      double dr = Zr[b4 + 3 * mq], di = Zi[b4 + 3 * mq];
      double apcr = ar + cr, apci = ai + ci;
      double amcr = ar - cr, amci = ai - ci;
      double bpdr = br + dr, bpdi = bi + di;
      double bmdr = br - dr, bmdi = bi - di;
      Zr[b4] = apcr + bpdr; Zi[b4] = apci + bpdi;
      int idx = j * tw;
      double w1r = Wc[idx], w1i = -Ws[idx];
      double w2r = w1r * w1r - w1i * w1i, w2i = 2.0 * w1r * w1i;
      double w3r = w2r * w1r - w2i * w1i, w3i = w2r * w1i + w2i * w1r;
      double t1r = amcr + bmdi, t1i = amci - bmdr;          // amc - i*bmd
      Zr[b4 + mq] = w1r * t1r - w1i * t1i; Zi[b4 + mq] = w1r * t1i + w1i * t1r;
      double t2r = apcr - bpdr, t2i = apci - bpdi;
      Zr[b4 + 2 * mq] = w2r * t2r - w2i * t2i; Zi[b4 + 2 * mq] = w2r * t2i + w2i * t2r;
      double t3r = amcr - bmdi, t3i = amci + bmdr;          // amc + i*bmd
      Zr[b4 + 3 * mq] = w3r * t3r - w3i * t3i; Zi[b4 + 3 * mq] = w3r * t3i + w3i * t3r;
    }
    __syncthreads();
  }
#pragma unroll
  for (int uu = 0; uu < 4; ++uu) {                           // final radix-2
    int u = tid + uu * TPB;
    int p0 = 2 * u, p1 = 2 * u + 1;
    double ar = Zr[p0], ai = Zi[p0], br = Zr[p1], bi = Zi[p1];
    Zr[p0] = ar + br; Zi[p0] = ai + bi;
    Zr[p1] = ar - br; Zi[p1] = ai - bi;
  }
  __syncthreads();

  // ---- magnitude^2 keys (fp64 compute, fp32-rounded monotone keys) ----
  for (int k = tid; k <= 2048; k += TPB)
    keyF[k] = (float)exactMag2(k, Zr, Zi, Uc, Us);
  __syncthreads();

  // ---- top-k threshold via 4-pass radix select on u32 keys ----
  int kk = kptr[0];
  if (kk > 2049) kk = 2049;
  if (kk < 1) kk = 1;
  unsigned int prefix = 0u, pmask = 0u, Tkey = 0u;
  bool haveT = false;
  int R = kk;
#pragma unroll
  for (int p = 0; p < 4; ++p) {
    if (!haveT) {  // uniform branch (haveT derived from LDS broadcast)
      const int sh = (p == 0) ? 23 : (p == 1) ? 14 : (p == 2) ? 5 : 0;
      for (int h = tid; h < 512; h += TPB) hist[h] = 0u;
      __syncthreads();
      for (int k = tid; k <= 2048; k += TPB) {
        unsigned int u = __float_as_uint(keyF[k]);
        if ((u & pmask) == prefix) atomicAdd(&hist[(u >> sh) & 511u], 1u);
      }
      __syncthreads();
      unsigned int h0 = hist[2 * tid], h1 = hist[2 * tid + 1];
      scanBuf[tid] = h0 + h1;
      __syncthreads();
      for (int off = 1; off < 256; off <<= 1) {   // inclusive suffix scan
        unsigned int v = scanBuf[tid] + ((tid + off < 256) ? scanBuf[tid + off] : 0u);
        __syncthreads();
        scanBuf[tid] = v;
        __syncthreads();
      }
      unsigned int incl = scanBuf[tid];
      unsigned int excl = incl - (h0 + h1);
      unsigned int Ru = (unsigned int)R;
      if (excl < Ru && Ru <= incl) {              // unique owner thread
        unsigned int cumTop = excl + h1;
        if (Ru <= cumTop) { bcD = 2 * tid + 1; bcR = Ru - excl;   bcCnt = h1; }
        else              { bcD = 2 * tid;     bcR = Ru - cumTop; bcCnt = h0; }
      }
      __syncthreads();
      prefix |= (bcD << sh);
      pmask |= (511u << sh);
      R = (int)bcR;
      if (bcCnt == 1u) {                          // unique boundary element: grab key
        for (int k = tid; k <= 2048; k += TPB) {
          unsigned int u = __float_as_uint(keyF[k]);
          if ((u & pmask) == prefix) bcT = u;
        }
        __syncthreads();
        Tkey = bcT;
        haveT = true;
      }
      __syncthreads();
    }
  }
  if (!haveT) Tkey = prefix;

  // counts above / equal
  if (tid == 0) { bcG = 0u; bcE = 0u; bcTieN = 0u; }
  __syncthreads();
  for (int k = tid; k <= 2048; k += TPB) {
    unsigned int u = __float_as_uint(keyF[k]);
    if (u > Tkey) atomicAdd(&bcG, 1u);
    else if (u == Tkey) atomicAdd(&bcE, 1u);
  }
  __syncthreads();
  int need = kk - (int)bcG;
  int e = (int)bcE;
  if (need >= e) {   // common path: keep everything >= Tkey (exactly kk kept)
    for (int k = tid; k <= 2048; k += TPB)
      maskArr[k] = (__float_as_uint(keyF[k]) >= Tkey) ? 1 : 0;
    __syncthreads();
  } else {           // rare: fp32 key collision at boundary -> exact fp64 tie-break
    for (int k = tid; k <= 2048; k += TPB) {
      unsigned int u = __float_as_uint(keyF[k]);
      maskArr[k] = (u > Tkey) ? 1 : 0;
      if (u == Tkey) {
        int pos = (int)atomicAdd(&bcTieN, 1u);
        if (pos < 64) tieIdx[pos] = k;
      }
    }
    __syncthreads();
    if (tid == 0) {
      int nt = (int)bcTieN; if (nt > 64) nt = 64;
      double vals[64];
      unsigned char chosen[64];
      for (int t = 0; t < nt; ++t) { vals[t] = exactMag2(tieIdx[t], Zr, Zi, Uc, Us); chosen[t] = 0; }
      int lim = (need < 64) ? need : 64;
      for (int s = 0; s < lim; ++s) {
        int best = -1;
        for (int t = 0; t < nt; ++t) {
          if (chosen[t]) continue;
          if (best < 0 || vals[t] > vals[best] ||
              (vals[t] == vals[best] && tieIdx[t] < tieIdx[best])) best = t;
        }
        if (best >= 0) { chosen[best] = 1; maskArr[tieIdx[best]] = 1; }
      }
    }
    __syncthreads();
  }

  // ---- filter + repack: Z'[k] from masked X[k], X[2048-k]; staged in registers ----
  double rzr[8], rzi[8];
#pragma unroll
  for (int jj = 0; jj < 8; ++jj) {
    int k = tid + TPB * jj;
    int kb = (2048 - k) & 2047;
    int pa = drev11(k), pb = drev11(kb);
    double zkr = Zr[pa], zki = Zi[pa];
    double zmr = Zr[pb], zmi = Zi[pb];
    double her = 0.5 * (zkr + zmr), hei = 0.5 * (zki - zmi);
    double hor = 0.5 * (zki + zmi), hoi = -0.5 * (zkr - zmr);
    double wr, wi; wn4096(k, Uc, Us, wr, wi);
    double whr = wr * hor - wi * hoi, whi = wr * hoi + wi * hor;   // W*Ho
    double x1r = her + whr, x1i = hei + whi;                        // X[k]
    double x2r = her - whr, x2i = -(hei - whi);                     // X[2048-k]
    double Am = maskArr[k] ? 1.0 : 0.0, Bm = maskArr[2048 - k] ? 1.0 : 0.0;
    double Ar2 = Am * x1r, Ai2 = Am * x1i;
    double Br2 = Bm * x2r, Bi2 = Bm * x2i;
    double sr_ = Ar2 + Br2, si_ = Ai2 - Bi2;                        // A + conj(B)
    double dr_ = Ar2 - Br2, di_ = Ai2 + Bi2;                        // A - conj(B)
    double tr_ = wr * dr_ + wi * di_, ti_ = wr * di_ - wi * dr_;    // conj(W)*(A-conj B)
    rzr[jj] = 0.5 * (sr_ - ti_);
    rzi[jj] = 0.5 * (si_ + tr_);
  }
  __syncthreads();
#pragma unroll
  for (int jj = 0; jj < 8; ++jj) {
    int k = tid + TPB * jj;
    int p = drev11(k);
    Zr[p] = rzr[jj]; Zi[p] = rzi[jj];
  }
  __syncthreads();

  // ---- inverse FFT: radix-2 then radix-4 DIT (digit-reversed -> natural) ----
#pragma unroll
  for (int uu = 0; uu < 4; ++uu) {
    int u = tid + uu * TPB;
    int p0 = 2 * u, p1 = 2 * u + 1;
    double ar = Zr[p0], ai = Zi[p0], br = Zr[p1], bi = Zi[p1];
    Zr[p0] = ar + br; Zi[p0] = ai + bi;
    Zr[p1] = ar - br; Zi[p1] = ai - bi;
  }
  __syncthreads();
#pragma unroll
  for (int n = 8; n <= 2048; n <<= 2) {
    const int mq = n >> 2;
    const int tw = 2048 / n;
#pragma unroll
    for (int uu = 0; uu < 2; ++uu) {
      int u = tid + uu * TPB;
      int blk = u / mq;
      int j = u - blk * mq;
      int b4 = blk * n + j;
      double y0r = Zr[b4], y0i = Zi[b4];
      double y1r = Zr[b4 + mq], y1i = Zi[b4 + mq];
      double y2r = Zr[b4 + 2 * mq], y2i = Zi[b4 + 2 * mq];
      double y3r = Zr[b4 + 3 * mq], y3i = Zi[b4 + 3 * mq];
      int idx = j * tw;
      double w1r = Wc[idx], w1i = Ws[idx];       // conj of forward twiddle
      double w2r = w1r * w1r - w1i * w1i, w2i = 2.0 * w1r * w1i;
      double w3r = w2r * w1r - w2i * w1i, w3i = w2r * w1i + w2i * w1r;
      double F1r = w1r * y1r - w1i * y1i, F1i = w1r * y1i + w1i * y1r;
      double F2r = w2r * y2r - w2i * y2i, F2i = w2r * y2i + w2i * y2r;
      double F3r = w3r * y3r - w3i * y3i, F3i = w3r * y3i + w3i * y3r;
      double s02r = y0r + F2r, s02i = y0i + F2i;
      double d02r = y0r - F2r, d02i = y0i - F2i;
      double s13r = F1r + F3r, s13i = F1i + F3i;
      double d13r = F1r - F3r, d13i = F1i - F3i;
      Zr[b4] = s02r + s13r;          Zi[b4] = s02i + s13i;
      Zr[b4 + mq] = d02r - d13i;     Zi[b4 + mq] = d02i + d13r;   // +i*d13
      Zr[b4 + 2 * mq] = s02r - s13r; Zi[b4 + 2 * mq] = s02i - s13i;
      Zr[b4 + 3 * mq] = d02r + d13i; Zi[b4 + 3 * mq] = d02i - d13r; // -i*d13
    }
    __syncthreads();
  }

  // ---- store (scale 1/2048 accounts for unnormalized fwd/inv pair) ----
  const double sc = 1.0 / 2048.0;
  for (int t = tid; t < 4096; t += TPB) {
    int n = t >> 1;
    double v = (t & 1) ? Zi[n] : Zr[n];
    dp[(size_t)t * strideT] = (float)(v * sc);
  }
}

extern "C" void kernel_launch(void* const* d_in, const int* in_sizes, int n_in,
                              void* d_out, int out_size, void* d_ws, size_t ws_size,
                              hipStream_t stream) {
  (void)in_sizes; (void)n_in; (void)out_size;
  const float* ts = (const float*)d_in[0];
  const int* kptr = (const int*)d_in[1];
  float* out = (float*)d_out;
  float* ws = (float*)d_ws;
  const int B = 64, S = 4096, C = 128;
  const size_t needWs = (size_t)B * S * C * sizeof(float);

  if (ws_size >= needWs) {
    // (B,S,C) -> (B,C,S) -> per-signal FFT/top-k in-place -> (B,C,S) -> (B,S,C)
    dim3 tb(32, 8);
    tpose_kernel<<<dim3(S / 32, C / 32, B), tb, 0, stream>>>(ts, ws, S, C);
    fourier_topk_kernel<<<B * C, TPB, 0, stream>>>(ws, ws, kptr, 1);
    tpose_kernel<<<dim3(C / 32, S / 32, B), tb, 0, stream>>>(ws, out, C, S);
  } else {
    // Fallback: direct strided access (XCD-swizzled block mapping keeps
    // 16-channel cache-line groups on one XCD's L2).
    fourier_topk_kernel<<<B * C, TPB, 0, stream>>>(ts, out, kptr, C);
  }
}

// Round 2
// 566.839 us; speedup vs baseline: 1.6302x; 1.6302x over previous
//
#include <hip/hip_runtime.h>
#include <math.h>

#ifndef M_PI
#define M_PI 3.14159265358979323846
#endif

#define TPB 256
// Zero-overhead LDS bank swizzle: bijective on [0,2048), makes every pow2
// stride (1,2,4,8,16,32,64,256,...) map <=2-way on banks (2-way is free, m136).
#define IDX(i) ((i) ^ (((i) >> 4) & 15) ^ (((i) >> 8) & 15))

// Digit-reverse for 2048 = 4^5 * 2, radix sequence [4,4,4,4,4,2] (DIF order).
__device__ __forceinline__ int drev11(int k) {
  return ((k & 3) << 9) | (((k >> 2) & 3) << 7) | (((k >> 4) & 3) << 5)
       | (((k >> 6) & 3) << 3) | (((k >> 8) & 3) << 1) | ((k >> 10) & 1);
}

// W_4096^k = e^{-i*pi*k/2048}, k in [0,2048]; Cc[m] = cos(pi*m/2048), m<=1025.
__device__ __forceinline__ void wn4096c(int k, const double* Cc,
                                        double& wr, double& wi) {
  int q = k >> 9, r = k & 511;
  const double H = 0.7071067811865476;
  double pr  = (q == 0) ? 1.0 : (q == 1) ? H    : (q == 2) ? 0.0  : (q == 3) ? -H : -1.0;
  double pii = (q == 0) ? 0.0 : (q == 1) ? -H   : (q == 2) ? -1.0 : (q == 3) ? -H : 0.0;
  double ur = Cc[r], ui = -Cc[1024 - r];   // cos, -sin
  wr = pr * ur - pii * ui;
  wi = pr * ui + pii * ur;
}

// |X[k]|^2 in fp64 from the digit-reversed, swizzled packed spectrum Z.
__device__ __forceinline__ double exactMag2(int k, const double* Zr, const double* Zi,
                                            const double* Cc) {
  int ka = k & 2047, kb = (2048 - k) & 2047;
  int pa = IDX(drev11(ka)), pb = IDX(drev11(kb));
  double zkr = Zr[pa], zki = Zi[pa], zmr = Zr[pb], zmi = Zi[pb];
  double her = 0.5 * (zkr + zmr), hei = 0.5 * (zki - zmi);
  double hor = 0.5 * (zki + zmi), hoi = -0.5 * (zkr - zmr);
  double wr, wi; wn4096c(k, Cc, wr, wi);
  double xr = her + wr * hor - wi * hoi;
  double xi = hei + wr * hoi + wi * hor;
  return xr * xr + xi * xi;
}

// Build Cc[m] = cos(pi*m/2048), m in [0,1025], in global ws (done once per launch).
__global__ void twid_build(double* __restrict__ Cg) {
  int m = blockIdx.x * 256 + threadIdx.x;
  if (m < 1026) Cg[m] = cos((M_PI / 2048.0) * (double)m);
}

// (B, R, Cd) -> (B, Cd, R) transpose, 64x64 tiles, float4 on both sides.
__global__ __launch_bounds__(256) void tposeV(const float* __restrict__ in,
                                              float* __restrict__ out,
                                              int R, int Cd) {
  __shared__ float tile[64][65];
  int t = threadIdx.x;
  int q = t & 15, r = t >> 4;
  int b = blockIdx.z;
  int c0 = blockIdx.x * 64, r0 = blockIdx.y * 64;
  const float4* in4 = reinterpret_cast<const float4*>(in + (size_t)b * R * Cd);
  float4* out4 = reinterpret_cast<float4*>(out + (size_t)b * R * Cd);
#pragma unroll
  for (int rr = r; rr < 64; rr += 16) {
    float4 v = in4[((size_t)(r0 + rr) * Cd + c0) / 4 + q];
    tile[rr][4 * q + 0] = v.x; tile[rr][4 * q + 1] = v.y;
    tile[rr][4 * q + 2] = v.z; tile[rr][4 * q + 3] = v.w;
  }
  __syncthreads();
#pragma unroll
  for (int cc = r; cc < 64; cc += 16) {
    float4 w;
    w.x = tile[4 * q + 0][cc]; w.y = tile[4 * q + 1][cc];
    w.z = tile[4 * q + 2][cc]; w.w = tile[4 * q + 3][cc];
    out4[((size_t)(c0 + cc) * R + r0) / 4 + q] = w;
  }
}

// One block per (b,c) signal: fp64 packed rfft -> top-k mask -> fp32 irfft.
// strideT==1: src/dst are (B,C,S) contiguous. strideT==128: direct (B,S,C).
__global__ __launch_bounds__(TPB, 3) void fourier_topk_kernel(
    const float* __restrict__ src, float* __restrict__ dst,
    const int* __restrict__ kptr, const double* __restrict__ Cg, int strideT) {
  __shared__ double Zr[2048], Zi[2048];          // 32 KB (swizzled indexing)
  __shared__ double Cc[1026];                    // 8.2 KB quarter-wave cos table
  __shared__ float keyF[2049];                   // 8.2 KB
  __shared__ unsigned int hist[256];
  __shared__ unsigned int scanB[256];
  __shared__ unsigned char maskA[2052];
  __shared__ int tieIdx[64];
  __shared__ unsigned int bcD, bcR, bcCnt, bcT, bcG, bcE, bcTieN;

  const int tid = threadIdx.x;
  // XCD-aware signal mapping (harmless for contiguous path, helps fallback).
  int i = blockIdx.x;
  int xj = i & 7, mm = i >> 3;
  int c = 16 * xj + (mm & 15);
  int b = mm >> 4;
  size_t base = (strideT == 1) ? ((size_t)(b * 128 + c)) * 4096
                               : ((size_t)b * 4096 * 128 + (size_t)c);
  const float* sp = src + base;
  float* dp = dst + base;

  // Table: load from global (fast path) or build in-kernel (fallback).
  if (Cg) { for (int m = tid; m < 1026; m += TPB) Cc[m] = Cg[m]; }
  else    { for (int m = tid; m < 1026; m += TPB) Cc[m] = cos((M_PI / 2048.0) * (double)m); }

  // Load: z[n] = x[2n] + i*x[2n+1]
  if (strideT == 1) {
    const float4* sp4 = reinterpret_cast<const float4*>(sp);
#pragma unroll
    for (int it = 0; it < 4; ++it) {
      int t4 = tid + TPB * it;
      float4 v = sp4[t4];
      int n0 = 2 * t4;
      Zr[IDX(n0)] = (double)v.x;     Zi[IDX(n0)] = (double)v.y;
      Zr[IDX(n0 + 1)] = (double)v.z; Zi[IDX(n0 + 1)] = (double)v.w;
    }
  } else {
    for (int t = tid; t < 4096; t += TPB) {
      float v = sp[(size_t)t * strideT];
      int n = t >> 1;
      if (t & 1) Zi[IDX(n)] = (double)v; else Zr[IDX(n)] = (double)v;
    }
  }
  __syncthreads();

  // ---- forward FFT (fp64): in-place radix-4 DIF, natural -> digit-reversed ----
#pragma unroll
  for (int st = 0; st <= 4; ++st) {
    const int n = 2048 >> (2 * st);        // 2048,512,128,32,8
    const int lm = 9 - 2 * st;             // log2(mq)
    const int mq = 1 << lm;
#pragma unroll
    for (int uu = 0; uu < 2; ++uu) {
      int u = tid + uu * TPB;
      int blk, j;
      if (lm >= 4) { blk = u >> lm; j = u & (mq - 1); }        // lanes: stride-1
      else { int lnb = 9 - lm; blk = u & ((1 << lnb) - 1); j = u >> lnb; } // stride-n
      int b4 = blk * n + j;
      int pa = IDX(b4), pb = IDX(b4 + mq), pc = IDX(b4 + 2 * mq), pd = IDX(b4 + 3 * mq);
      double ar = Zr[pa], ai = Zi[pa];
      double br = Zr[pb], bi = Zi[pb];
      double cr = Zr[pc], ci = Zi[pc];
      double dr = Zr[pd], di = Zi[pd];
      double apcr = ar + cr, apci = ai + ci;
      double amcr = ar - cr, amci = ai - ci;
      double bpdr = br + dr, bpdi = bi + di;
      double bmdr = br - dr, bmdi = bi - di;
      Zr[pa] = apcr + bpdr; Zi[pa] = apci + bpdi;
      int ix = j << (2 * st);                                  // j * (2048/n) < 512
      double w1r = Cc[2 * ix], w1i = -Cc[1024 - 2 * ix];
      double w2r = w1r * w1r - w1i * w1i, w2i = 2.0 * w1r * w1i;
      double w3r = w2r * w1r - w2i * w1i, w3i = w2r * w1i + w2i * w1r;
      double t1r = amcr + bmdi, t1i = amci - bmdr;             // amc - i*bmd
      Zr[pb] = w1r * t1r - w1i * t1i; Zi[pb] = w1r * t1i + w1i * t1r;
      double t2r = apcr - bpdr, t2i = apci - bpdi;
      Zr[pc] = w2r * t2r - w2i * t2i; Zi[pc] = w2r * t2i + w2i * t2r;
      double t3r = amcr - bmdi, t3i = amci + bmdr;             // amc + i*bmd
      Zr[pd] = w3r * t3r - w3i * t3i; Zi[pd] = w3r * t3i + w3i * t3r;
    }
    __syncthreads();
  }
#pragma unroll
  for (int uu = 0; uu < 4; ++uu) {                             // final radix-2
    int u = tid + uu * TPB;
    int p0 = IDX(2 * u), p1 = IDX(2 * u + 1);
    double ar = Zr[p0], ai = Zi[p0], br = Zr[p1], bi = Zi[p1];
    Zr[p0] = ar + br; Zi[p0] = ai + bi;
    Zr[p1] = ar - br; Zi[p1] = ai - bi;
  }
  __syncthreads();

  // ---- magnitude^2 keys (fp64 compute, fp32-rounded monotone keys) ----
  for (int k = tid; k <= 2048; k += TPB)
    keyF[k] = (float)exactMag2(k, Zr, Zi, Cc);
  __syncthreads();

  // ---- top-k threshold via 4-pass 8-bit radix select on u32 keys ----
  int kk = kptr[0];
  if (kk > 2049) kk = 2049;
  if (kk < 1) kk = 1;
  unsigned int prefix = 0u, pmask = 0u, Tkey = 0u;
  bool haveT = false;
  int R = kk;
#pragma unroll 1
  for (int p = 0; p < 4; ++p) {
    if (!haveT) {  // uniform (haveT from LDS broadcast)
      const int sh = 24 - 8 * p;
      hist[tid] = 0u;
      __syncthreads();
      for (int k = tid; k <= 2048; k += TPB) {
        unsigned int u = __float_as_uint(keyF[k]);
        if ((u & pmask) == prefix) atomicAdd(&hist[(u >> sh) & 255u], 1u);
      }
      __syncthreads();
      unsigned int h = hist[tid];
      scanB[tid] = h;
      __syncthreads();
      for (int off = 1; off < 256; off <<= 1) {   // inclusive suffix scan
        unsigned int v = scanB[tid] + ((tid + off < 256) ? scanB[tid + off] : 0u);
        __syncthreads();
        scanB[tid] = v;
        __syncthreads();
      }
      unsigned int incl = scanB[tid];
      unsigned int excl = incl - h;
      unsigned int Ru = (unsigned int)R;
      if (excl < Ru && Ru <= incl) { bcD = (unsigned)tid; bcR = Ru - excl; bcCnt = h; }
      __syncthreads();
      prefix |= (bcD << sh);
      pmask |= (255u << sh);
      R = (int)bcR;
      if (bcCnt == 1u) {                          // unique boundary element
        for (int k = tid; k <= 2048; k += TPB) {
          unsigned int u = __float_as_uint(keyF[k]);
          if ((u & pmask) == prefix) bcT = u;
        }
        __syncthreads();
        Tkey = bcT;
        haveT = true;
      }
      __syncthreads();
    }
  }
  if (!haveT) Tkey = prefix;

  // counts above / equal
  if (tid == 0) { bcG = 0u; bcE = 0u; bcTieN = 0u; }
  __syncthreads();
  for (int k = tid; k <= 2048; k += TPB) {
    unsigned int u = __float_as_uint(keyF[k]);
    if (u > Tkey) atomicAdd(&bcG, 1u);
    else if (u == Tkey) atomicAdd(&bcE, 1u);
  }
  __syncthreads();
  int need = kk - (int)bcG;
  int e = (int)bcE;
  if (need >= e) {   // common path: keep everything >= Tkey (exactly kk kept)
    for (int k = tid; k <= 2048; k += TPB)
      maskA[k] = (__float_as_uint(keyF[k]) >= Tkey) ? 1 : 0;
    __syncthreads();
  } else {           // rare: fp32 key collision at boundary -> exact fp64 tie-break
    for (int k = tid; k <= 2048; k += TPB) {
      unsigned int u = __float_as_uint(keyF[k]);
      maskA[k] = (u > Tkey) ? 1 : 0;
      if (u == Tkey) {
        int pos = (int)atomicAdd(&bcTieN, 1u);
        if (pos < 64) tieIdx[pos] = k;
      }
    }
    __syncthreads();
    if (tid == 0) {
      int nt = (int)bcTieN; if (nt > 64) nt = 64;
      double vals[64];
      unsigned char chosen[64];
      for (int t = 0; t < nt; ++t) { vals[t] = exactMag2(tieIdx[t], Zr, Zi, Cc); chosen[t] = 0; }
      int lim = (need < 64) ? need : 64;
      for (int s = 0; s < lim; ++s) {
        int best = -1;
        for (int t = 0; t < nt; ++t) {
          if (chosen[t]) continue;
          if (best < 0 || vals[t] > vals[best] ||
              (vals[t] == vals[best] && tieIdx[t] < tieIdx[best])) best = t;
        }
        if (best >= 0) { chosen[best] = 1; maskA[tieIdx[best]] = 1; }
      }
    }
    __syncthreads();
  }

  // ---- filter + repack (fp64 math), result staged fp32 in registers ----
  float rfr[8], rfi[8];
#pragma unroll
  for (int jj = 0; jj < 8; ++jj) {
    int k = tid + TPB * jj;
    int kb = (2048 - k) & 2047;
    int pa = IDX(drev11(k)), pb = IDX(drev11(kb));
    double zkr = Zr[pa], zki = Zi[pa];
    double zmr = Zr[pb], zmi = Zi[pb];
    double her = 0.5 * (zkr + zmr), hei = 0.5 * (zki - zmi);
    double hor = 0.5 * (zki + zmi), hoi = -0.5 * (zkr - zmr);
    double wr, wi; wn4096c(k, Cc, wr, wi);
    double whr = wr * hor - wi * hoi, whi = wr * hoi + wi * hor;   // W*Ho
    double x1r = her + whr, x1i = hei + whi;                        // X[k]
    double x2r = her - whr, x2i = -(hei - whi);                     // X[2048-k]
    double Am = maskA[k] ? 1.0 : 0.0, Bm = maskA[2048 - k] ? 1.0 : 0.0;
    double Ar2 = Am * x1r, Ai2 = Am * x1i;
    double Br2 = Bm * x2r, Bi2 = Bm * x2i;
    double sr_ = Ar2 + Br2, si_ = Ai2 - Bi2;                        // A + conj(B)
    double dr_ = Ar2 - Br2, di_ = Ai2 + Bi2;                        // A - conj(B)
    double tr_ = wr * dr_ + wi * di_, ti_ = wr * di_ - wi * dr_;    // conj(W)*(A-conj B)
    rfr[jj] = (float)(0.5 * (sr_ - ti_));
    rfi[jj] = (float)(0.5 * (si_ + tr_));
  }
  __syncthreads();

  // ---- inverse FFT in fp32, aliased into the fp64 Z storage ----
  float* Fr = reinterpret_cast<float*>(Zr);
  float* Fi = reinterpret_cast<float*>(Zi);
#pragma unroll
  for (int jj = 0; jj < 8; ++jj) {
    int k = tid + TPB * jj;
    int p = IDX(drev11(k));
    Fr[p] = rfr[jj]; Fi[p] = rfi[jj];
  }
  __syncthreads();
#pragma unroll
  for (int uu = 0; uu < 4; ++uu) {                               // radix-2 first
    int u = tid + uu * TPB;
    int p0 = IDX(2 * u), p1 = IDX(2 * u + 1);
    float ar = Fr[p0], ai = Fi[p0], br = Fr[p1], bi = Fi[p1];
    Fr[p0] = ar + br; Fi[p0] = ai + bi;
    Fr[p1] = ar - br; Fi[p1] = ai - bi;
  }
  __syncthreads();
#pragma unroll
  for (int st = 4; st >= 0; --st) {
    const int n = 2048 >> (2 * st);        // 8,32,128,512,2048
    const int lm = 9 - 2 * st;
    const int mq = 1 << lm;
#pragma unroll
    for (int uu = 0; uu < 2; ++uu) {
      int u = tid + uu * TPB;
      int blk, j;
      if (lm >= 4) { blk = u >> lm; j = u & (mq - 1); }
      else { int lnb = 9 - lm; blk = u & ((1 << lnb) - 1); j = u >> lnb; }
      int b4 = blk * n + j;
      int pa = IDX(b4), pb = IDX(b4 + mq), pc = IDX(b4 + 2 * mq), pd = IDX(b4 + 3 * mq);
      float y0r = Fr[pa], y0i = Fi[pa];
      float y1r = Fr[pb], y1i = Fi[pb];
      float y2r = Fr[pc], y2i = Fi[pc];
      float y3r = Fr[pd], y3i = Fi[pd];
      int ix = j << (2 * st);
      float w1r = (float)Cc[2 * ix], w1i = (float)Cc[1024 - 2 * ix];  // conj twiddle
      float w2r = w1r * w1r - w1i * w1i, w2i = 2.0f * w1r * w1i;
      float w3r = w2r * w1r - w2i * w1i, w3i = w2r * w1i + w2i * w1r;
      float F1r = w1r * y1r - w1i * y1i, F1i = w1r * y1i + w1i * y1r;
      float F2r = w2r * y2r - w2i * y2i, F2i = w2r * y2i + w2i * y2r;
      float F3r = w3r * y3r - w3i * y3i, F3i = w3r * y3i + w3i * y3r;
      float s02r = y0r + F2r, s02i = y0i + F2i;
      float d02r = y0r - F2r, d02i = y0i - F2i;
      float s13r = F1r + F3r, s13i = F1i + F3i;
      float d13r = F1r - F3r, d13i = F1i - F3i;
      Fr[pa] = s02r + s13r; Fi[pa] = s02i + s13i;
      Fr[pb] = d02r - d13i; Fi[pb] = d02i + d13r;    // +i*d13
      Fr[pc] = s02r - s13r; Fi[pc] = s02i - s13i;
      Fr[pd] = d02r + d13i; Fi[pd] = d02i - d13r;    // -i*d13
    }
    __syncthreads();
  }

  // ---- store (scale 1/2048 accounts for unnormalized fwd/inv pair) ----
  const float scf = 1.0f / 2048.0f;
  if (strideT == 1) {
    float4* dp4 = reinterpret_cast<float4*>(dp);
#pragma unroll
    for (int it = 0; it < 4; ++it) {
      int t4 = tid + TPB * it;
      int n0 = 2 * t4;
      float4 v;
      v.x = Fr[IDX(n0)] * scf;     v.y = Fi[IDX(n0)] * scf;
      v.z = Fr[IDX(n0 + 1)] * scf; v.w = Fi[IDX(n0 + 1)] * scf;
      dp4[t4] = v;
    }
  } else {
    for (int t = tid; t < 4096; t += TPB) {
      int n = t >> 1;
      float v = (t & 1) ? Fi[IDX(n)] : Fr[IDX(n)];
      dp[(size_t)t * strideT] = v * scf;
    }
  }
}

extern "C" void kernel_launch(void* const* d_in, const int* in_sizes, int n_in,
                              void* d_out, int out_size, void* d_ws, size_t ws_size,
                              hipStream_t stream) {
  (void)in_sizes; (void)n_in; (void)out_size;
  const float* ts = (const float*)d_in[0];
  const int* kptr = (const int*)d_in[1];
  float* out = (float*)d_out;
  float* ws = (float*)d_ws;
  const int B = 64, S = 4096, C = 128;
  const size_t sigBytes = (size_t)B * S * C * sizeof(float);
  const size_t tabBytes = 1026 * sizeof(double);

  if (ws_size >= sigBytes + tabBytes) {
    double* Cg = (double*)((char*)d_ws + sigBytes);
    twid_build<<<5, 256, 0, stream>>>(Cg);
    // (B,S,C) -> (B,C,S) -> per-signal FFT/top-k in-place -> (B,S,C)
    tposeV<<<dim3(C / 64, S / 64, B), 256, 0, stream>>>(ts, ws, S, C);
    fourier_topk_kernel<<<B * C, TPB, 0, stream>>>(ws, ws, kptr, Cg, 1);
    tposeV<<<dim3(S / 64, C / 64, B), 256, 0, stream>>>(ws, out, C, S);
  } else if (ws_size >= sigBytes) {
    tposeV<<<dim3(C / 64, S / 64, B), 256, 0, stream>>>(ts, ws, S, C);
    fourier_topk_kernel<<<B * C, TPB, 0, stream>>>(ws, ws, kptr, nullptr, 1);
    tposeV<<<dim3(S / 64, C / 64, B), 256, 0, stream>>>(ws, out, C, S);
  } else {
    // Fallback: direct strided access (XCD-swizzled block->signal mapping).
    fourier_topk_kernel<<<B * C, TPB, 0, stream>>>(ts, out, kptr, nullptr, C);
  }
}